// Round 14
// baseline (570.577 us; speedup 1.0000x reference)
//
#include <hip/hip_runtime.h>
#include <math.h>

#define HID 128
#define NGAUSS 50
#define TBL 2048
#define TBL2 8192
#define DMAX 8.6605f
#define LDX 136   // fp16 row pitch for A/Y LDS tiles
#define PGRID 768

typedef _Float16 h4 __attribute__((ext_vector_type(4)));
typedef _Float16 f16x8 __attribute__((ext_vector_type(8)));
typedef float f32x4 __attribute__((ext_vector_type(4)));

__device__ __forceinline__ float sspf(float x) {
  float ax = fabsf(x);
  return fmaxf(x, 0.0f) + log1pf(expf(-ax)) - 0.69314718055994530942f;
}

// ---- Build W(d) lookup table (fp32, coarse): tab[l][ti][j]
__global__ __launch_bounds__(128) void build_table_k(
    const float* __restrict__ w1, const float* __restrict__ b1,
    const float* __restrict__ w2, const float* __restrict__ b2,
    float* __restrict__ tab) {
  int l = blockIdx.x >> 11;
  int ti = blockIdx.x & (TBL - 1);
  int j = threadIdx.x;
  __shared__ float rbf[NGAUSS];
  __shared__ float v1[HID];
  const float step = DMAX / (float)(TBL - 1);
  float d = ti * step;
  if (j < NGAUSS) {
    const float gstep = 10.0f / 49.0f;
    const float gcoeff = -12.005f;
    float diff = d - j * gstep;
    rbf[j] = expf(gcoeff * diff * diff);
  }
  __syncthreads();
  float s = b1[l * HID + j];
  const float* w1p = w1 + l * NGAUSS * HID + j;
  for (int g = 0; g < NGAUSS; g++) s = fmaf(rbf[g], w1p[g * HID], s);
  v1[j] = sspf(s);
  __syncthreads();
  float s2 = b2[l * HID + j];
  const float* w2p = w2 + l * HID * HID + j;
  for (int k = 0; k < HID; k++) s2 = fmaf(v1[k], w2p[k * HID], s2);
  float C = 0.5f * (cosf(d * 0.3141592653589793f) + 1.0f);
  tab[((size_t)l * TBL + ti) * HID + j] = s2 * C;
}

// ---- upsample coarse fp32 lerp table -> fine fp16 nearest table [l][TBL2][HID]
__global__ __launch_bounds__(256) void upsample_k(
    const float* __restrict__ tab, _Float16* __restrict__ tabh) {
  int idx = blockIdx.x * 256 + threadIdx.x;
  if (idx >= 3 * TBL2 * HID) return;
  int ch = idx & 127;
  int i = (idx >> 7) & (TBL2 - 1);
  int l = idx >> 20;
  float t = (float)i * ((float)(TBL - 1) / (float)(TBL2 - 1));
  int i0 = min((int)t, TBL - 2);
  float f = t - (float)i0;
  const float* base = tab + ((size_t)l * TBL + i0) * HID + ch;
  tabh[idx] = (_Float16)fmaf(f, base[HID] - base[0], base[0]);
}

// ---- swizzle 9 128x128 weights + out1_w (128x64) into B-fragment order
__global__ __launch_bounds__(256) void wswz10_k(
    const float* __restrict__ lin1, const float* __restrict__ lin2,
    const float* __restrict__ intw, const float* __restrict__ out1w,
    _Float16* __restrict__ out) {
  int b = blockIdx.x;
  int t = threadIdx.x;
  if (b < 9) {
    const float* src = (b < 3 ? lin1 : (b < 6 ? lin2 : intw)) + (size_t)(b % 3) * HID * HID;
    _Float16* dst = out + (size_t)b * 16384;
    for (int i = t; i < 16384; i += 256) {
      int j = i & 7;
      int lane = (i >> 3) & 63;
      int kk = (i >> 9) & 3;
      int ntc = i >> 11;
      int n = ntc * 16 + (lane & 15);
      int k = kk * 32 + (lane >> 4) * 8 + j;
      dst[i] = (_Float16)src[k * HID + n];
    }
  } else {
    _Float16* dst = out + (size_t)9 * 16384;
    for (int i = t; i < 8192; i += 256) {
      int j = i & 7;
      int lane = (i >> 3) & 63;
      int kk = (i >> 9) & 3;
      int ntc = i >> 11;
      int n = ntc * 16 + (lane & 15);
      int k = kk * 32 + (lane >> 4) * 8 + j;
      dst[i] = (_Float16)out1w[k * 64 + n];
    }
  }
}

// ---- h16 = (fp16) emb[z]
__global__ __launch_bounds__(256) void emb_gather_k(
    const int* __restrict__ z, const float* __restrict__ emb,
    _Float16* __restrict__ h16, int N) {
  int i4 = blockIdx.x * 256 + threadIdx.x;
  if (i4 >= N * 32) return;
  int a = i4 >> 5;
  float4 v = ((const float4*)emb)[z[a] * 32 + (i4 & 31)];
  h4 o;
  o.x = (_Float16)v.x; o.y = (_Float16)v.y;
  o.z = (_Float16)v.z; o.w = (_Float16)v.w;
  ((h4*)h16)[i4] = o;
}

// ---- bucket (col>>6) histogram, LDS-aggregated
__global__ __launch_bounds__(256) void bcount_k(
    const int* __restrict__ col, int* __restrict__ bcount, int E, int nbuck) {
  __shared__ int hist[1024];
  int t = threadIdx.x;
  int e0 = blockIdx.x * 2048;
  for (int j = t; j < nbuck; j += 256) hist[j] = 0;
  __syncthreads();
#pragma unroll
  for (int u = 0; u < 8; u++) {
    int e = e0 + u * 256 + t;
    if (e < E) atomicAdd(&hist[col[e] >> 6], 1);
  }
  __syncthreads();
  for (int j = t; j < nbuck; j += 256)
    if (hist[j]) atomicAdd(&bcount[j], hist[j]);
}

// ---- exclusive scan of bucket counts (single block)
__global__ __launch_bounds__(256) void bucket_scan_k(
    const int* __restrict__ bcount, int* __restrict__ bstart,
    int* __restrict__ bcur, int nbuck, int* __restrict__ starts, int N) {
  __shared__ int sh[256];
  int t = threadIdx.x;
  int chunk = (nbuck + 255) / 256;
  int b0 = t * chunk;
  int c[8];
  int s = 0;
  for (int j = 0; j < chunk; j++) {
    int idx = b0 + j;
    int v = (idx < nbuck) ? bcount[idx] : 0;
    c[j] = v;
    s += v;
  }
  sh[t] = s;
  __syncthreads();
  for (int o = 1; o < 256; o <<= 1) {
    int v = (t >= o) ? sh[t - o] : 0;
    __syncthreads();
    sh[t] += v;
    __syncthreads();
  }
  int p = (t == 0) ? 0 : sh[t - 1];
  for (int j = 0; j < chunk; j++) {
    int idx = b0 + j;
    if (idx < nbuck) {
      bstart[idx] = p;
      bcur[idx] = p;
      p += c[j];
    }
  }
  if (t == 255) {
    bstart[nbuck] = p;
    starts[N] = p;
  }
}

// ---- level-1 scatter: distance inline, key64 into 64-atom bucket chunks
__global__ __launch_bounds__(256) void scatterA_k(
    const int* __restrict__ row, const int* __restrict__ col,
    const float* __restrict__ pos, int* __restrict__ bcur,
    unsigned long long* __restrict__ tmp, int E, int nbuck) {
  __shared__ int hist[1024];
  __shared__ int base[1024];
  int t = threadIdx.x;
  int e0 = blockIdx.x * 2048;
  for (int j = t; j < nbuck; j += 256) hist[j] = 0;
  __syncthreads();
  int bkt[8];
  int rnk[8];
  unsigned long long key[8];
#pragma unroll
  for (int u = 0; u < 8; u++) {
    int e = e0 + u * 256 + t;
    bkt[u] = -1;
    if (e < E) {
      int r = row[e], c = col[e];
      float dx = pos[r * 3 + 0] - pos[c * 3 + 0];
      float dy = pos[r * 3 + 1] - pos[c * 3 + 1];
      float dz = pos[r * 3 + 2] - pos[c * 3 + 2];
      float d = sqrtf(dx * dx + dy * dy + dz * dz);
      const float inv2 = (float)(TBL2 - 1) / DMAX;
      int q = min((int)(d * inv2 + 0.5f), TBL2 - 1);
      unsigned int pay = ((unsigned int)r << 13) | (unsigned int)q;
      key[u] = ((unsigned long long)pay << 6) | (unsigned long long)(c & 63);
      bkt[u] = c >> 6;
      rnk[u] = atomicAdd(&hist[bkt[u]], 1);
    }
  }
  __syncthreads();
  for (int j = t; j < nbuck; j += 256)
    base[j] = hist[j] ? atomicAdd(&bcur[j], hist[j]) : 0;
  __syncthreads();
#pragma unroll
  for (int u = 0; u < 8; u++)
    if (bkt[u] >= 0) tmp[(size_t)base[bkt[u]] + rnk[u]] = key[u];
}

// ---- level-2: per-bucket per-atom counts -> starts, then local scatter
__global__ __launch_bounds__(256) void scatterB_k(
    const unsigned long long* __restrict__ tmp, const int* __restrict__ bstart,
    int* __restrict__ starts, unsigned int* __restrict__ payload, int N) {
  int j = blockIdx.x;
  int t = threadIdx.x;
  __shared__ int cnt[64];
  __shared__ int cur[64];
  int rs = bstart[j], re = bstart[j + 1];
  if (t < 64) cnt[t] = 0;
  __syncthreads();
  for (int e = rs + t; e < re; e += 256)
    atomicAdd(&cnt[(int)(tmp[e] & 63)], 1);
  __syncthreads();
  if (t < 64) {
    int mine = cnt[t];
    int v = mine;
    for (int o = 1; o < 64; o <<= 1) {
      int u = __shfl_up(v, o, 64);
      if (t >= o) v += u;
    }
    int excl = v - mine;
    int c = j * 64 + t;
    if (c < N) starts[c] = rs + excl;
    cur[t] = rs + excl;
  }
  __syncthreads();
  for (int e = rs + t; e < re; e += 256) {
    unsigned long long k = tmp[e];
    int p = atomicAdd(&cur[(int)(k & 63)], 1);
    payload[p] = (unsigned int)(k >> 6);
  }
}

// ======== persistent GEMM kernels: 32-atom tiles, weights streamed from L2 =====
// 4 waves: g=w&1 (atom group of 16), c=w>>1 (col half of 64)

// ---- x16 = in16 @ W   (fp16 in, fp16 out; no bias/act)
__global__ __launch_bounds__(256, 4) void lin_p_k(
    const _Float16* __restrict__ in16, const _Float16* __restrict__ Wg,
    _Float16* __restrict__ out16, int N, int ntiles) {
  __shared__ __align__(16) _Float16 Xs[32 * LDX];
  __shared__ __align__(16) _Float16 Ys[32 * LDX];
  int t = threadIdx.x;
  int lane = t & 63, w = t >> 6;
  int g = w & 1, c = w >> 1;
  int mrow = lane & 15, quad = lane >> 4;
  f32x4 zero = {0.f, 0.f, 0.f, 0.f};
  for (int tile = blockIdx.x; tile < ntiles; tile += gridDim.x) {
    int a0 = tile * 32;
#pragma unroll
    for (int p = 0; p < 2; p++) {
      int id = t + p * 256;
      int a = id >> 4, kg = id & 15;
      uint4 v = make_uint4(0, 0, 0, 0);
      if (a0 + a < N) v = ((const uint4*)in16)[(size_t)(a0 + a) * 16 + kg];
      *(uint4*)&Xs[a * LDX + kg * 8] = v;
    }
    __syncthreads();
    f16x8 af[4];
#pragma unroll
    for (int kk = 0; kk < 4; kk++)
      af[kk] = *(const f16x8*)&Xs[(g * 16 + mrow) * LDX + kk * 32 + quad * 8];
    f32x4 acc[4];
#pragma unroll
    for (int i = 0; i < 4; i++) acc[i] = zero;
#pragma unroll
    for (int kk = 0; kk < 4; kk++) {
#pragma unroll
      for (int nt = 0; nt < 4; nt++) {
        f16x8 bf = *(const f16x8*)(Wg + ((((c * 4 + nt) * 4 + kk) << 9) + lane * 8));
        acc[nt] = __builtin_amdgcn_mfma_f32_16x16x32_f16(af[kk], bf, acc[nt], 0, 0, 0);
      }
    }
#pragma unroll
    for (int nt = 0; nt < 4; nt++) {
      int colv = c * 64 + nt * 16 + mrow;
#pragma unroll
      for (int r = 0; r < 4; r++)
        Ys[(g * 16 + quad * 4 + r) * LDX + colv] = (_Float16)acc[nt][r];
    }
    __syncthreads();
#pragma unroll
    for (int p = 0; p < 2; p++) {
      int id = t + p * 256;
      int a = id >> 4, kg = id & 15;
      if (a0 + a < N)
        ((uint4*)out16)[(size_t)(a0 + a) * 16 + kg] = *(uint4*)&Ys[a * LDX + kg * 8];
    }
  }
}

// ---- fused: y = ssp(agg @ W2 + b2); h16 += y @ W3 + b3
__global__ __launch_bounds__(256, 4) void ssp_res_p_k(
    const _Float16* __restrict__ agg16, const _Float16* __restrict__ W2g,
    const float* __restrict__ b2, const _Float16* __restrict__ W3g,
    const float* __restrict__ b3, _Float16* __restrict__ h16, int N, int ntiles) {
  __shared__ __align__(16) _Float16 Xs[32 * LDX];
  __shared__ __align__(16) _Float16 Ys[32 * LDX];
  int t = threadIdx.x;
  int lane = t & 63, w = t >> 6;
  int g = w & 1, c = w >> 1;
  int mrow = lane & 15, quad = lane >> 4;
  float br2[4], br3[4];
#pragma unroll
  for (int nt = 0; nt < 4; nt++) {
    br2[nt] = b2[c * 64 + nt * 16 + mrow];
    br3[nt] = b3[c * 64 + nt * 16 + mrow];
  }
  f32x4 zero = {0.f, 0.f, 0.f, 0.f};
  for (int tile = blockIdx.x; tile < ntiles; tile += gridDim.x) {
    int a0 = tile * 32;
#pragma unroll
    for (int p = 0; p < 2; p++) {
      int id = t + p * 256;
      int a = id >> 4, kg = id & 15;
      uint4 v = make_uint4(0, 0, 0, 0);
      if (a0 + a < N) v = ((const uint4*)agg16)[(size_t)(a0 + a) * 16 + kg];
      *(uint4*)&Xs[a * LDX + kg * 8] = v;
    }
    __syncthreads();
    f16x8 af[4];
#pragma unroll
    for (int kk = 0; kk < 4; kk++)
      af[kk] = *(const f16x8*)&Xs[(g * 16 + mrow) * LDX + kk * 32 + quad * 8];
    f32x4 acc[4];
#pragma unroll
    for (int i = 0; i < 4; i++) acc[i] = zero;
#pragma unroll
    for (int kk = 0; kk < 4; kk++) {
#pragma unroll
      for (int nt = 0; nt < 4; nt++) {
        f16x8 bf = *(const f16x8*)(W2g + ((((c * 4 + nt) * 4 + kk) << 9) + lane * 8));
        acc[nt] = __builtin_amdgcn_mfma_f32_16x16x32_f16(af[kk], bf, acc[nt], 0, 0, 0);
      }
    }
#pragma unroll
    for (int nt = 0; nt < 4; nt++) {
      int colv = c * 64 + nt * 16 + mrow;
#pragma unroll
      for (int r = 0; r < 4; r++)
        Ys[(g * 16 + quad * 4 + r) * LDX + colv] = (_Float16)sspf(acc[nt][r] + br2[nt]);
    }
    __syncthreads();
    // GEMM2: A = y rows from Ys
#pragma unroll
    for (int kk = 0; kk < 4; kk++)
      af[kk] = *(const f16x8*)&Ys[(g * 16 + mrow) * LDX + kk * 32 + quad * 8];
    __syncthreads();   // all reads of Ys done before overwrite
#pragma unroll
    for (int i = 0; i < 4; i++) acc[i] = zero;
#pragma unroll
    for (int kk = 0; kk < 4; kk++) {
#pragma unroll
      for (int nt = 0; nt < 4; nt++) {
        f16x8 bf = *(const f16x8*)(W3g + ((((c * 4 + nt) * 4 + kk) << 9) + lane * 8));
        acc[nt] = __builtin_amdgcn_mfma_f32_16x16x32_f16(af[kk], bf, acc[nt], 0, 0, 0);
      }
    }
#pragma unroll
    for (int nt = 0; nt < 4; nt++) {
      int colv = c * 64 + nt * 16 + mrow;
#pragma unroll
      for (int r = 0; r < 4; r++)
        Ys[(g * 16 + quad * 4 + r) * LDX + colv] = (_Float16)(acc[nt][r] + br3[nt]);
    }
    __syncthreads();
    // h16 += Ys (coalesced uint4 RMW)
#pragma unroll
    for (int p = 0; p < 2; p++) {
      int id = t + p * 256;
      int a = id >> 4, kg = id & 15;
      if (a0 + a < N) {
        f16x8 hv = *(const f16x8*)&((const uint4*)h16)[(size_t)(a0 + a) * 16 + kg];
        f16x8 yv = *(f16x8*)&Ys[a * LDX + kg * 8];
        f16x8 o;
#pragma unroll
        for (int j = 0; j < 8; j++) o[j] = (_Float16)((float)hv[j] + (float)yv[j]);
        ((uint4*)h16)[(size_t)(a0 + a) * 16 + kg] = *(uint4*)&o;
      }
    }
  }
}

// ---- energy + segmented molecule flush (batch sorted: <=3 atomics per tile)
__global__ __launch_bounds__(256, 4) void energy_p_k(
    const _Float16* __restrict__ h16, const _Float16* __restrict__ Wg,
    const float* __restrict__ o1b, const float* __restrict__ o2w,
    const float* __restrict__ o2b, const int* __restrict__ batch,
    float* __restrict__ out, int N, int ntiles) {
  __shared__ __align__(16) _Float16 Xs[32 * LDX];
  __shared__ float ebuf[32];
  __shared__ int bat[32];
  int t = threadIdx.x;
  int lane = t & 63, w = t >> 6;
  int g = w & 1, c = w >> 1;
  int mrow = lane & 15, quad = lane >> 4;
  float br[2], wr[2];
#pragma unroll
  for (int nt = 0; nt < 2; nt++) {
    int colv = c * 32 + nt * 16 + mrow;
    br[nt] = o1b[colv];
    wr[nt] = o2w[colv];
  }
  float o2b0 = o2b[0];
  if (t < 32) ebuf[t] = 0.f;
  __syncthreads();
  f32x4 zero = {0.f, 0.f, 0.f, 0.f};
  for (int tile = blockIdx.x; tile < ntiles; tile += gridDim.x) {
    int a0 = tile * 32;
#pragma unroll
    for (int p = 0; p < 2; p++) {
      int id = t + p * 256;
      int a = id >> 4, kg = id & 15;
      uint4 v = make_uint4(0, 0, 0, 0);
      if (a0 + a < N) v = ((const uint4*)h16)[(size_t)(a0 + a) * 16 + kg];
      *(uint4*)&Xs[a * LDX + kg * 8] = v;
    }
    if (t < 32) bat[t] = (a0 + t < N) ? batch[a0 + t] : -1;
    __syncthreads();
    f16x8 af[4];
#pragma unroll
    for (int kk = 0; kk < 4; kk++)
      af[kk] = *(const f16x8*)&Xs[(g * 16 + mrow) * LDX + kk * 32 + quad * 8];
    f32x4 acc[2];
    acc[0] = zero; acc[1] = zero;
#pragma unroll
    for (int kk = 0; kk < 4; kk++) {
#pragma unroll
      for (int nt = 0; nt < 2; nt++) {
        f16x8 bf = *(const f16x8*)(Wg + ((((c * 2 + nt) * 4 + kk) << 9) + lane * 8));
        acc[nt] = __builtin_amdgcn_mfma_f32_16x16x32_f16(af[kk], bf, acc[nt], 0, 0, 0);
      }
    }
    float ss[4] = {0.f, 0.f, 0.f, 0.f};
#pragma unroll
    for (int nt = 0; nt < 2; nt++)
#pragma unroll
      for (int r = 0; r < 4; r++) ss[r] += sspf(acc[nt][r] + br[nt]) * wr[nt];
#pragma unroll
    for (int r = 0; r < 4; r++) {
      ss[r] += __shfl_xor(ss[r], 1);
      ss[r] += __shfl_xor(ss[r], 2);
      ss[r] += __shfl_xor(ss[r], 4);
      ss[r] += __shfl_xor(ss[r], 8);
      if (mrow == 0) atomicAdd(&ebuf[g * 16 + quad * 4 + r], ss[r]);
    }
    __syncthreads();
    if (t == 0) {
      float acs = 0.f;
      int pm = -1;
      for (int i = 0; i < 32; i++) {
        int m = bat[i];
        float e = ebuf[i];
        ebuf[i] = 0.f;
        if (m < 0) break;
        if (m != pm) {
          if (pm >= 0) atomicAdd(&out[pm], acs);
          acs = 0.f;
          pm = m;
        }
        acs += e + o2b0;
      }
      if (pm >= 0) atomicAdd(&out[pm], acs);
    }
  }
}

// ---- agg16[a] = (fp16) sum_{e: col=a} x16[row_e] * tabh[tq_e]
// phase-split: batch 16 loads in flight, then 4 independent pk_fma chains
__global__ __launch_bounds__(256) void aggregate_k(
    const int* __restrict__ starts, const unsigned int* __restrict__ payload,
    const _Float16* __restrict__ x16, const _Float16* __restrict__ tabh,
    _Float16* __restrict__ agg16, int N) {
  int a = blockIdx.x * 4 + (threadIdx.x >> 6);
  if (a >= N) return;
  int lane = threadIdx.x & 63;
  int half = lane >> 5;
  int sl = lane & 31;
  int s = starts[a], e_end = starts[a + 1];
  float4 accf = make_float4(0.f, 0.f, 0.f, 0.f);
  const h4 z4 = {(_Float16)0.f, (_Float16)0.f, (_Float16)0.f, (_Float16)0.f};
  int i = s;
  for (; i + 16 <= e_end; i += 16) {
    unsigned int p[8];
#pragma unroll
    for (int u = 0; u < 8; u++) p[u] = payload[i + 2 * u + half];
    h4 tw[8], xr[8];
#pragma unroll
    for (int u = 0; u < 8; u++) {
      int tq = (int)(p[u] & 8191u);
      int r = (int)(p[u] >> 13);
      tw[u] = *(const h4*)&tabh[(size_t)tq * HID + sl * 4];
      xr[u] = *(const h4*)&x16[(size_t)r * HID + sl * 4];
    }
    h4 a0 = z4, a1 = z4, a2 = z4, a3 = z4;
    a0 += tw[0] * xr[0];
    a1 += tw[1] * xr[1];
    a2 += tw[2] * xr[2];
    a3 += tw[3] * xr[3];
    a0 += tw[4] * xr[4];
    a1 += tw[5] * xr[5];
    a2 += tw[6] * xr[6];
    a3 += tw[7] * xr[7];
    h4 b0 = a0 + a1, b1 = a2 + a3;
    accf.x += (float)b0.x + (float)b1.x;
    accf.y += (float)b0.y + (float)b1.y;
    accf.z += (float)b0.z + (float)b1.z;
    accf.w += (float)b0.w + (float)b1.w;
  }
  {
    h4 a0 = z4, a1 = z4;
    int k = 0;
    for (; i + 2 <= e_end; i += 2, k++) {
      unsigned int p = payload[i + half];
      int tq = (int)(p & 8191u);
      int r = (int)(p >> 13);
      h4 tw = *(const h4*)&tabh[(size_t)tq * HID + sl * 4];
      h4 xr = *(const h4*)&x16[(size_t)r * HID + sl * 4];
      if (k & 1) a1 += tw * xr; else a0 += tw * xr;
    }
    if (i < e_end && half == 0) {
      unsigned int p = payload[i];
      int tq = (int)(p & 8191u);
      int r = (int)(p >> 13);
      h4 tw = *(const h4*)&tabh[(size_t)tq * HID + sl * 4];
      h4 xr = *(const h4*)&x16[(size_t)r * HID + sl * 4];
      a0 += tw * xr;
    }
    h4 b0 = a0 + a1;
    accf.x += (float)b0.x;
    accf.y += (float)b0.y;
    accf.z += (float)b0.z;
    accf.w += (float)b0.w;
  }
  accf.x += __shfl_xor(accf.x, 32);
  accf.y += __shfl_xor(accf.y, 32);
  accf.z += __shfl_xor(accf.z, 32);
  accf.w += __shfl_xor(accf.w, 32);
  if (half == 0) {
    h4 o;
    o.x = (_Float16)accf.x; o.y = (_Float16)accf.y;
    o.z = (_Float16)accf.z; o.w = (_Float16)accf.w;
    *(h4*)&agg16[(size_t)a * HID + sl * 4] = o;
  }
}

extern "C" void kernel_launch(void* const* d_in, const int* in_sizes, int n_in,
                              void* d_out, int out_size, void* d_ws, size_t ws_size,
                              hipStream_t stream) {
  const int* z = (const int*)d_in[0];
  const float* pos = (const float*)d_in[1];
  const int* batch = (const int*)d_in[2];
  const int* eidx = (const int*)d_in[3];
  const float* emb = (const float*)d_in[4];
  const float* mlp1_w = (const float*)d_in[5];
  const float* mlp1_b = (const float*)d_in[6];
  const float* mlp2_w = (const float*)d_in[7];
  const float* mlp2_b = (const float*)d_in[8];
  const float* lin1_w = (const float*)d_in[9];
  const float* lin2_w = (const float*)d_in[10];
  const float* lin2_b = (const float*)d_in[11];
  const float* int_w = (const float*)d_in[12];
  const float* int_b = (const float*)d_in[13];
  const float* out1_w = (const float*)d_in[14];
  const float* out1_b = (const float*)d_in[15];
  const float* out2_w = (const float*)d_in[16];
  const float* out2_b = (const float*)d_in[17];
  float* out = (float*)d_out;

  const int N = in_sizes[0];
  const int E = in_sizes[3] / 2;
  const int* row = eidx;
  const int* col = eidx + E;
  const int nbuck = (N + 63) / 64;
  const int ntiles = (N + 31) / 32;

  char* ws = (char*)d_ws;
  size_t off = 0;
  auto alloc = [&](size_t bytes) -> void* {
    void* p = ws + off;
    off = (off + bytes + 255) & ~(size_t)255;
    return p;
  };
  _Float16* h16 = (_Float16*)alloc((size_t)N * HID * 2);
  _Float16* x16 = (_Float16*)alloc((size_t)N * HID * 2);
  size_t agg_bytes = (size_t)N * HID * 2;
  size_t tmp_bytes = (size_t)E * 8 + 16;
  void* agg_union = alloc(agg_bytes > tmp_bytes ? agg_bytes : tmp_bytes);
  _Float16* agg16 = (_Float16*)agg_union;
  unsigned long long* tmp = (unsigned long long*)agg_union;
  unsigned int* payload = (unsigned int*)alloc((size_t)E * 4 + 16);
  int* starts = (int*)alloc((size_t)(N + 1) * 4);
  int* bcount = (int*)alloc((size_t)nbuck * 4);
  int* bstart = (int*)alloc((size_t)(nbuck + 1) * 4);
  int* bcur = (int*)alloc((size_t)nbuck * 4);
  float* tab = (float*)alloc((size_t)3 * TBL * HID * 4);
  _Float16* tabh = (_Float16*)alloc((size_t)3 * TBL2 * HID * 2);
  _Float16* Wsw = (_Float16*)alloc((size_t)10 * 16384 * 2);
  (void)ws_size;

  hipMemsetAsync(bcount, 0, (size_t)nbuck * 4, stream);
  hipMemsetAsync(out, 0, (size_t)out_size * 4, stream);

  build_table_k<<<3 * TBL, 128, 0, stream>>>(mlp1_w, mlp1_b, mlp2_w, mlp2_b, tab);
  upsample_k<<<(3 * TBL2 * HID + 255) / 256, 256, 0, stream>>>(tab, tabh);
  wswz10_k<<<10, 256, 0, stream>>>(lin1_w, lin2_w, int_w, out1_w, Wsw);
  emb_gather_k<<<(N * 32 + 255) / 256, 256, 0, stream>>>(z, emb, h16, N);
  bcount_k<<<(E + 2047) / 2048, 256, 0, stream>>>(col, bcount, E, nbuck);
  bucket_scan_k<<<1, 256, 0, stream>>>(bcount, bstart, bcur, nbuck, starts, N);
  scatterA_k<<<(E + 2047) / 2048, 256, 0, stream>>>(row, col, pos, bcur, tmp, E, nbuck);
  scatterB_k<<<nbuck, 256, 0, stream>>>(tmp, bstart, starts, payload, N);

  int pg = PGRID < ntiles ? PGRID : ntiles;
  for (int l = 0; l < 3; l++) {
    lin_p_k<<<pg, 256, 0, stream>>>(h16, Wsw + (size_t)l * 16384, x16, N, ntiles);
    aggregate_k<<<(N + 3) / 4, 256, 0, stream>>>(starts, payload, x16,
                                                 tabh + (size_t)l * TBL2 * HID, agg16, N);
    ssp_res_p_k<<<pg, 256, 0, stream>>>(agg16, Wsw + (size_t)(3 + l) * 16384,
                                        lin2_b + (size_t)l * HID,
                                        Wsw + (size_t)(6 + l) * 16384,
                                        int_b + (size_t)l * HID, h16, N, ntiles);
  }
  energy_p_k<<<pg, 256, 0, stream>>>(h16, Wsw + (size_t)9 * 16384, out1_b, out2_w,
                                     out2_b, batch, out, N, ntiles);
}

// Round 15
// 562.467 us; speedup vs baseline: 1.0144x; 1.0144x over previous
//
#include <hip/hip_runtime.h>
#include <math.h>

#define HID 128
#define NGAUSS 50
#define TBL 2048
#define TBL2 8192
#define DMAX 8.6605f
#define LDX 136   // fp16 row pitch for A/Y LDS tiles

typedef _Float16 h4 __attribute__((ext_vector_type(4)));
typedef _Float16 f16x8 __attribute__((ext_vector_type(8)));
typedef float f32x4 __attribute__((ext_vector_type(4)));

__device__ __forceinline__ float sspf(float x) {
  float ax = fabsf(x);
  return fmaxf(x, 0.0f) + log1pf(expf(-ax)) - 0.69314718055994530942f;
}

// ---- Build W(d) lookup table (fp32, coarse): tab[l][ti][j]
__global__ __launch_bounds__(128) void build_table_k(
    const float* __restrict__ w1, const float* __restrict__ b1,
    const float* __restrict__ w2, const float* __restrict__ b2,
    float* __restrict__ tab) {
  int l = blockIdx.x >> 11;
  int ti = blockIdx.x & (TBL - 1);
  int j = threadIdx.x;
  __shared__ float rbf[NGAUSS];
  __shared__ float v1[HID];
  const float step = DMAX / (float)(TBL - 1);
  float d = ti * step;
  if (j < NGAUSS) {
    const float gstep = 10.0f / 49.0f;
    const float gcoeff = -12.005f;
    float diff = d - j * gstep;
    rbf[j] = expf(gcoeff * diff * diff);
  }
  __syncthreads();
  float s = b1[l * HID + j];
  const float* w1p = w1 + l * NGAUSS * HID + j;
  for (int g = 0; g < NGAUSS; g++) s = fmaf(rbf[g], w1p[g * HID], s);
  v1[j] = sspf(s);
  __syncthreads();
  float s2 = b2[l * HID + j];
  const float* w2p = w2 + l * HID * HID + j;
  for (int k = 0; k < HID; k++) s2 = fmaf(v1[k], w2p[k * HID], s2);
  float C = 0.5f * (cosf(d * 0.3141592653589793f) + 1.0f);
  tab[((size_t)l * TBL + ti) * HID + j] = s2 * C;
}

// ---- upsample coarse fp32 lerp table -> fine fp16 nearest table [l][TBL2][HID]
__global__ __launch_bounds__(256) void upsample_k(
    const float* __restrict__ tab, _Float16* __restrict__ tabh) {
  int idx = blockIdx.x * 256 + threadIdx.x;
  if (idx >= 3 * TBL2 * HID) return;
  int ch = idx & 127;
  int i = (idx >> 7) & (TBL2 - 1);
  int l = idx >> 20;
  float t = (float)i * ((float)(TBL - 1) / (float)(TBL2 - 1));
  int i0 = min((int)t, TBL - 2);
  float f = t - (float)i0;
  const float* base = tab + ((size_t)l * TBL + i0) * HID + ch;
  tabh[idx] = (_Float16)fmaf(f, base[HID] - base[0], base[0]);
}

// ---- swizzle 9 128x128 weights + out1_w (128x64) into B-fragment order
__global__ __launch_bounds__(256) void wswz10_k(
    const float* __restrict__ lin1, const float* __restrict__ lin2,
    const float* __restrict__ intw, const float* __restrict__ out1w,
    _Float16* __restrict__ out) {
  int b = blockIdx.x;
  int t = threadIdx.x;
  if (b < 9) {
    const float* src = (b < 3 ? lin1 : (b < 6 ? lin2 : intw)) + (size_t)(b % 3) * HID * HID;
    _Float16* dst = out + (size_t)b * 16384;
    for (int i = t; i < 16384; i += 256) {
      int j = i & 7;
      int lane = (i >> 3) & 63;
      int kk = (i >> 9) & 3;
      int ntc = i >> 11;
      int n = ntc * 16 + (lane & 15);
      int k = kk * 32 + (lane >> 4) * 8 + j;
      dst[i] = (_Float16)src[k * HID + n];
    }
  } else {
    _Float16* dst = out + (size_t)9 * 16384;
    for (int i = t; i < 8192; i += 256) {
      int j = i & 7;
      int lane = (i >> 3) & 63;
      int kk = (i >> 9) & 3;
      int ntc = i >> 11;
      int n = ntc * 16 + (lane & 15);
      int k = kk * 32 + (lane >> 4) * 8 + j;
      dst[i] = (_Float16)out1w[k * 64 + n];
    }
  }
}

// ---- bucket (col>>6) histogram, LDS-aggregated
__global__ __launch_bounds__(256) void bcount_k(
    const int* __restrict__ col, int* __restrict__ bcount, int E, int nbuck) {
  __shared__ int hist[1024];
  int t = threadIdx.x;
  int e0 = blockIdx.x * 2048;
  for (int j = t; j < nbuck; j += 256) hist[j] = 0;
  __syncthreads();
#pragma unroll
  for (int u = 0; u < 8; u++) {
    int e = e0 + u * 256 + t;
    if (e < E) atomicAdd(&hist[col[e] >> 6], 1);
  }
  __syncthreads();
  for (int j = t; j < nbuck; j += 256)
    if (hist[j]) atomicAdd(&bcount[j], hist[j]);
}

// ---- exclusive scan of bucket counts (single block)
__global__ __launch_bounds__(256) void bucket_scan_k(
    const int* __restrict__ bcount, int* __restrict__ bstart,
    int* __restrict__ bcur, int nbuck, int* __restrict__ starts, int N) {
  __shared__ int sh[256];
  int t = threadIdx.x;
  int chunk = (nbuck + 255) / 256;
  int b0 = t * chunk;
  int c[8];
  int s = 0;
  for (int j = 0; j < chunk; j++) {
    int idx = b0 + j;
    int v = (idx < nbuck) ? bcount[idx] : 0;
    c[j] = v;
    s += v;
  }
  sh[t] = s;
  __syncthreads();
  for (int o = 1; o < 256; o <<= 1) {
    int v = (t >= o) ? sh[t - o] : 0;
    __syncthreads();
    sh[t] += v;
    __syncthreads();
  }
  int p = (t == 0) ? 0 : sh[t - 1];
  for (int j = 0; j < chunk; j++) {
    int idx = b0 + j;
    if (idx < nbuck) {
      bstart[idx] = p;
      bcur[idx] = p;
      p += c[j];
    }
  }
  if (t == 255) {
    bstart[nbuck] = p;
    starts[N] = p;
  }
}

// ---- level-1 scatter: distance inline, key64 into 64-atom bucket chunks
__global__ __launch_bounds__(256) void scatterA_k(
    const int* __restrict__ row, const int* __restrict__ col,
    const float* __restrict__ pos, int* __restrict__ bcur,
    unsigned long long* __restrict__ tmp, int E, int nbuck) {
  __shared__ int hist[1024];
  __shared__ int base[1024];
  int t = threadIdx.x;
  int e0 = blockIdx.x * 2048;
  for (int j = t; j < nbuck; j += 256) hist[j] = 0;
  __syncthreads();
  int bkt[8];
  int rnk[8];
  unsigned long long key[8];
#pragma unroll
  for (int u = 0; u < 8; u++) {
    int e = e0 + u * 256 + t;
    bkt[u] = -1;
    if (e < E) {
      int r = row[e], c = col[e];
      float dx = pos[r * 3 + 0] - pos[c * 3 + 0];
      float dy = pos[r * 3 + 1] - pos[c * 3 + 1];
      float dz = pos[r * 3 + 2] - pos[c * 3 + 2];
      float d = sqrtf(dx * dx + dy * dy + dz * dz);
      const float inv2 = (float)(TBL2 - 1) / DMAX;
      int q = min((int)(d * inv2 + 0.5f), TBL2 - 1);
      unsigned int pay = ((unsigned int)r << 13) | (unsigned int)q;
      key[u] = ((unsigned long long)pay << 6) | (unsigned long long)(c & 63);
      bkt[u] = c >> 6;
      rnk[u] = atomicAdd(&hist[bkt[u]], 1);
    }
  }
  __syncthreads();
  for (int j = t; j < nbuck; j += 256)
    base[j] = hist[j] ? atomicAdd(&bcur[j], hist[j]) : 0;
  __syncthreads();
#pragma unroll
  for (int u = 0; u < 8; u++)
    if (bkt[u] >= 0) tmp[(size_t)base[bkt[u]] + rnk[u]] = key[u];
}

// ---- level-2: per-bucket per-atom counts -> starts, then local scatter
__global__ __launch_bounds__(256) void scatterB_k(
    const unsigned long long* __restrict__ tmp, const int* __restrict__ bstart,
    int* __restrict__ starts, unsigned int* __restrict__ payload, int N) {
  int j = blockIdx.x;
  int t = threadIdx.x;
  __shared__ int cnt[64];
  __shared__ int cur[64];
  int rs = bstart[j], re = bstart[j + 1];
  if (t < 64) cnt[t] = 0;
  __syncthreads();
  for (int e = rs + t; e < re; e += 256)
    atomicAdd(&cnt[(int)(tmp[e] & 63)], 1);
  __syncthreads();
  if (t < 64) {
    int mine = cnt[t];
    int v = mine;
    for (int o = 1; o < 64; o <<= 1) {
      int u = __shfl_up(v, o, 64);
      if (t >= o) v += u;
    }
    int excl = v - mine;
    int c = j * 64 + t;
    if (c < N) starts[c] = rs + excl;
    cur[t] = rs + excl;
  }
  __syncthreads();
  for (int e = rs + t; e < re; e += 256) {
    unsigned long long k = tmp[e];
    int p = atomicAdd(&cur[(int)(k & 63)], 1);
    payload[p] = (unsigned int)(k >> 6);
  }
}

// ======== persistent GEMM kernels: 32-atom tiles, weights streamed from L2 =====
// 4 waves: g=w&1 (atom group of 16), c=w>>1 (col half of 64)

// ---- layer 0: h16 = (fp16)emb[z] (store), x16 = h16 @ W1_0
__global__ __launch_bounds__(256, 4) void lin_emb_p_k(
    const int* __restrict__ z, const float* __restrict__ emb,
    const _Float16* __restrict__ Wg, _Float16* __restrict__ h16,
    _Float16* __restrict__ x16, int N, int ntiles) {
  __shared__ __align__(16) _Float16 Xs[32 * LDX];
  __shared__ __align__(16) _Float16 Ys[32 * LDX];
  __shared__ int zi[32];
  int t = threadIdx.x;
  int lane = t & 63, w = t >> 6;
  int g = w & 1, c = w >> 1;
  int mrow = lane & 15, quad = lane >> 4;
  f32x4 zero = {0.f, 0.f, 0.f, 0.f};
  for (int tile = blockIdx.x; tile < ntiles; tile += gridDim.x) {
    int a0 = tile * 32;
    if (t < 32) zi[t] = (a0 + t < N) ? z[a0 + t] : 0;
    __syncthreads();
#pragma unroll
    for (int p = 0; p < 2; p++) {
      int id = t + p * 256;
      int a = id >> 4, kg = id & 15;   // 8 halves = 8 floats from emb
      const float* er = emb + (size_t)zi[a] * HID + kg * 8;
      float4 e0 = *(const float4*)er;
      float4 e1 = *(const float4*)(er + 4);
      f16x8 o;
      o[0] = (_Float16)e0.x; o[1] = (_Float16)e0.y;
      o[2] = (_Float16)e0.z; o[3] = (_Float16)e0.w;
      o[4] = (_Float16)e1.x; o[5] = (_Float16)e1.y;
      o[6] = (_Float16)e1.z; o[7] = (_Float16)e1.w;
      *(f16x8*)&Xs[a * LDX + kg * 8] = o;
      if (a0 + a < N)
        ((uint4*)h16)[(size_t)(a0 + a) * 16 + kg] = *(uint4*)&o;
    }
    __syncthreads();
    f16x8 af[4];
#pragma unroll
    for (int kk = 0; kk < 4; kk++)
      af[kk] = *(const f16x8*)&Xs[(g * 16 + mrow) * LDX + kk * 32 + quad * 8];
    f32x4 acc[4];
#pragma unroll
    for (int i = 0; i < 4; i++) acc[i] = zero;
#pragma unroll
    for (int kk = 0; kk < 4; kk++) {
#pragma unroll
      for (int nt = 0; nt < 4; nt++) {
        f16x8 bf = *(const f16x8*)(Wg + ((((c * 4 + nt) * 4 + kk) << 9) + lane * 8));
        acc[nt] = __builtin_amdgcn_mfma_f32_16x16x32_f16(af[kk], bf, acc[nt], 0, 0, 0);
      }
    }
#pragma unroll
    for (int nt = 0; nt < 4; nt++) {
      int colv = c * 64 + nt * 16 + mrow;
#pragma unroll
      for (int r = 0; r < 4; r++)
        Ys[(g * 16 + quad * 4 + r) * LDX + colv] = (_Float16)acc[nt][r];
    }
    __syncthreads();
#pragma unroll
    for (int p = 0; p < 2; p++) {
      int id = t + p * 256;
      int a = id >> 4, kg = id & 15;
      if (a0 + a < N)
        ((uint4*)x16)[(size_t)(a0 + a) * 16 + kg] = *(uint4*)&Ys[a * LDX + kg * 8];
    }
  }
}

// ---- x16 = in16 @ W   (fp16 in, fp16 out; no bias/act)
__global__ __launch_bounds__(256, 4) void lin_p_k(
    const _Float16* __restrict__ in16, const _Float16* __restrict__ Wg,
    _Float16* __restrict__ out16, int N, int ntiles) {
  __shared__ __align__(16) _Float16 Xs[32 * LDX];
  __shared__ __align__(16) _Float16 Ys[32 * LDX];
  int t = threadIdx.x;
  int lane = t & 63, w = t >> 6;
  int g = w & 1, c = w >> 1;
  int mrow = lane & 15, quad = lane >> 4;
  f32x4 zero = {0.f, 0.f, 0.f, 0.f};
  for (int tile = blockIdx.x; tile < ntiles; tile += gridDim.x) {
    int a0 = tile * 32;
#pragma unroll
    for (int p = 0; p < 2; p++) {
      int id = t + p * 256;
      int a = id >> 4, kg = id & 15;
      uint4 v = make_uint4(0, 0, 0, 0);
      if (a0 + a < N) v = ((const uint4*)in16)[(size_t)(a0 + a) * 16 + kg];
      *(uint4*)&Xs[a * LDX + kg * 8] = v;
    }
    __syncthreads();
    f16x8 af[4];
#pragma unroll
    for (int kk = 0; kk < 4; kk++)
      af[kk] = *(const f16x8*)&Xs[(g * 16 + mrow) * LDX + kk * 32 + quad * 8];
    f32x4 acc[4];
#pragma unroll
    for (int i = 0; i < 4; i++) acc[i] = zero;
#pragma unroll
    for (int kk = 0; kk < 4; kk++) {
#pragma unroll
      for (int nt = 0; nt < 4; nt++) {
        f16x8 bf = *(const f16x8*)(Wg + ((((c * 4 + nt) * 4 + kk) << 9) + lane * 8));
        acc[nt] = __builtin_amdgcn_mfma_f32_16x16x32_f16(af[kk], bf, acc[nt], 0, 0, 0);
      }
    }
#pragma unroll
    for (int nt = 0; nt < 4; nt++) {
      int colv = c * 64 + nt * 16 + mrow;
#pragma unroll
      for (int r = 0; r < 4; r++)
        Ys[(g * 16 + quad * 4 + r) * LDX + colv] = (_Float16)acc[nt][r];
    }
    __syncthreads();
#pragma unroll
    for (int p = 0; p < 2; p++) {
      int id = t + p * 256;
      int a = id >> 4, kg = id & 15;
      if (a0 + a < N)
        ((uint4*)out16)[(size_t)(a0 + a) * 16 + kg] = *(uint4*)&Ys[a * LDX + kg * 8];
    }
  }
}

// ---- y16 = (fp16) ssp(agg16 @ W + b)
__global__ __launch_bounds__(256, 4) void ssp_p_k(
    const _Float16* __restrict__ agg16, const _Float16* __restrict__ Wg,
    const float* __restrict__ bias, _Float16* __restrict__ y16, int N, int ntiles) {
  __shared__ __align__(16) _Float16 Xs[32 * LDX];
  __shared__ __align__(16) _Float16 Ys[32 * LDX];
  int t = threadIdx.x;
  int lane = t & 63, w = t >> 6;
  int g = w & 1, c = w >> 1;
  int mrow = lane & 15, quad = lane >> 4;
  float br[4];
#pragma unroll
  for (int nt = 0; nt < 4; nt++) br[nt] = bias[c * 64 + nt * 16 + mrow];
  f32x4 zero = {0.f, 0.f, 0.f, 0.f};
  for (int tile = blockIdx.x; tile < ntiles; tile += gridDim.x) {
    int a0 = tile * 32;
#pragma unroll
    for (int p = 0; p < 2; p++) {
      int id = t + p * 256;
      int a = id >> 4, kg = id & 15;
      uint4 v = make_uint4(0, 0, 0, 0);
      if (a0 + a < N) v = ((const uint4*)agg16)[(size_t)(a0 + a) * 16 + kg];
      *(uint4*)&Xs[a * LDX + kg * 8] = v;
    }
    __syncthreads();
    f16x8 af[4];
#pragma unroll
    for (int kk = 0; kk < 4; kk++)
      af[kk] = *(const f16x8*)&Xs[(g * 16 + mrow) * LDX + kk * 32 + quad * 8];
    f32x4 acc[4];
#pragma unroll
    for (int i = 0; i < 4; i++) acc[i] = zero;
#pragma unroll
    for (int kk = 0; kk < 4; kk++) {
#pragma unroll
      for (int nt = 0; nt < 4; nt++) {
        f16x8 bf = *(const f16x8*)(Wg + ((((c * 4 + nt) * 4 + kk) << 9) + lane * 8));
        acc[nt] = __builtin_amdgcn_mfma_f32_16x16x32_f16(af[kk], bf, acc[nt], 0, 0, 0);
      }
    }
#pragma unroll
    for (int nt = 0; nt < 4; nt++) {
      int colv = c * 64 + nt * 16 + mrow;
#pragma unroll
      for (int r = 0; r < 4; r++)
        Ys[(g * 16 + quad * 4 + r) * LDX + colv] = (_Float16)sspf(acc[nt][r] + br[nt]);
    }
    __syncthreads();
#pragma unroll
    for (int p = 0; p < 2; p++) {
      int id = t + p * 256;
      int a = id >> 4, kg = id & 15;
      if (a0 + a < N)
        ((uint4*)y16)[(size_t)(a0 + a) * 16 + kg] = *(uint4*)&Ys[a * LDX + kg * 8];
    }
  }
}

// ---- h16 += y16 @ W + b   (fp16 RMW on h)
__global__ __launch_bounds__(256, 4) void res_p_k(
    const _Float16* __restrict__ y16, const _Float16* __restrict__ Wg,
    const float* __restrict__ bias, _Float16* __restrict__ h16, int N, int ntiles) {
  __shared__ __align__(16) _Float16 Xs[32 * LDX];
  __shared__ __align__(16) _Float16 Ys[32 * LDX];
  int t = threadIdx.x;
  int lane = t & 63, w = t >> 6;
  int g = w & 1, c = w >> 1;
  int mrow = lane & 15, quad = lane >> 4;
  float br[4];
#pragma unroll
  for (int nt = 0; nt < 4; nt++) br[nt] = bias[c * 64 + nt * 16 + mrow];
  f32x4 zero = {0.f, 0.f, 0.f, 0.f};
  for (int tile = blockIdx.x; tile < ntiles; tile += gridDim.x) {
    int a0 = tile * 32;
#pragma unroll
    for (int p = 0; p < 2; p++) {
      int id = t + p * 256;
      int a = id >> 4, kg = id & 15;
      uint4 v = make_uint4(0, 0, 0, 0);
      if (a0 + a < N) v = ((const uint4*)y16)[(size_t)(a0 + a) * 16 + kg];
      *(uint4*)&Xs[a * LDX + kg * 8] = v;
    }
    __syncthreads();
    f16x8 af[4];
#pragma unroll
    for (int kk = 0; kk < 4; kk++)
      af[kk] = *(const f16x8*)&Xs[(g * 16 + mrow) * LDX + kk * 32 + quad * 8];
    f32x4 acc[4];
#pragma unroll
    for (int i = 0; i < 4; i++) acc[i] = zero;
#pragma unroll
    for (int kk = 0; kk < 4; kk++) {
#pragma unroll
      for (int nt = 0; nt < 4; nt++) {
        f16x8 bf = *(const f16x8*)(Wg + ((((c * 4 + nt) * 4 + kk) << 9) + lane * 8));
        acc[nt] = __builtin_amdgcn_mfma_f32_16x16x32_f16(af[kk], bf, acc[nt], 0, 0, 0);
      }
    }
#pragma unroll
    for (int nt = 0; nt < 4; nt++) {
      int colv = c * 64 + nt * 16 + mrow;
#pragma unroll
      for (int r = 0; r < 4; r++)
        Ys[(g * 16 + quad * 4 + r) * LDX + colv] = (_Float16)(acc[nt][r] + br[nt]);
    }
    __syncthreads();
#pragma unroll
    for (int p = 0; p < 2; p++) {
      int id = t + p * 256;
      int a = id >> 4, kg = id & 15;
      if (a0 + a < N) {
        f16x8 hv = *(const f16x8*)&((const uint4*)h16)[(size_t)(a0 + a) * 16 + kg];
        f16x8 yv = *(f16x8*)&Ys[a * LDX + kg * 8];
        f16x8 o;
#pragma unroll
        for (int j = 0; j < 8; j++) o[j] = (_Float16)((float)hv[j] + (float)yv[j]);
        ((uint4*)h16)[(size_t)(a0 + a) * 16 + kg] = *(uint4*)&o;
      }
    }
  }
}

// ---- energy + segmented molecule flush (batch sorted: <=3 atomics per tile)
__global__ __launch_bounds__(256, 4) void energy_p_k(
    const _Float16* __restrict__ h16, const _Float16* __restrict__ Wg,
    const float* __restrict__ o1b, const float* __restrict__ o2w,
    const float* __restrict__ o2b, const int* __restrict__ batch,
    float* __restrict__ out, int N, int ntiles) {
  __shared__ __align__(16) _Float16 Xs[32 * LDX];
  __shared__ float ebuf[32];
  __shared__ int bat[32];
  int t = threadIdx.x;
  int lane = t & 63, w = t >> 6;
  int g = w & 1, c = w >> 1;
  int mrow = lane & 15, quad = lane >> 4;
  float br[2], wr[2];
#pragma unroll
  for (int nt = 0; nt < 2; nt++) {
    int colv = c * 32 + nt * 16 + mrow;
    br[nt] = o1b[colv];
    wr[nt] = o2w[colv];
  }
  float o2b0 = o2b[0];
  if (t < 32) ebuf[t] = 0.f;
  __syncthreads();
  f32x4 zero = {0.f, 0.f, 0.f, 0.f};
  for (int tile = blockIdx.x; tile < ntiles; tile += gridDim.x) {
    int a0 = tile * 32;
#pragma unroll
    for (int p = 0; p < 2; p++) {
      int id = t + p * 256;
      int a = id >> 4, kg = id & 15;
      uint4 v = make_uint4(0, 0, 0, 0);
      if (a0 + a < N) v = ((const uint4*)h16)[(size_t)(a0 + a) * 16 + kg];
      *(uint4*)&Xs[a * LDX + kg * 8] = v;
    }
    if (t < 32) bat[t] = (a0 + t < N) ? batch[a0 + t] : -1;
    __syncthreads();
    f16x8 af[4];
#pragma unroll
    for (int kk = 0; kk < 4; kk++)
      af[kk] = *(const f16x8*)&Xs[(g * 16 + mrow) * LDX + kk * 32 + quad * 8];
    f32x4 acc[2];
    acc[0] = zero; acc[1] = zero;
#pragma unroll
    for (int kk = 0; kk < 4; kk++) {
#pragma unroll
      for (int nt = 0; nt < 2; nt++) {
        f16x8 bf = *(const f16x8*)(Wg + ((((c * 2 + nt) * 4 + kk) << 9) + lane * 8));
        acc[nt] = __builtin_amdgcn_mfma_f32_16x16x32_f16(af[kk], bf, acc[nt], 0, 0, 0);
      }
    }
    float ss[4] = {0.f, 0.f, 0.f, 0.f};
#pragma unroll
    for (int nt = 0; nt < 2; nt++)
#pragma unroll
      for (int r = 0; r < 4; r++) ss[r] += sspf(acc[nt][r] + br[nt]) * wr[nt];
#pragma unroll
    for (int r = 0; r < 4; r++) {
      ss[r] += __shfl_xor(ss[r], 1);
      ss[r] += __shfl_xor(ss[r], 2);
      ss[r] += __shfl_xor(ss[r], 4);
      ss[r] += __shfl_xor(ss[r], 8);
      if (mrow == 0) atomicAdd(&ebuf[g * 16 + quad * 4 + r], ss[r]);
    }
    __syncthreads();
    if (t == 0) {
      float acs = 0.f;
      int pm = -1;
      for (int i = 0; i < 32; i++) {
        int m = bat[i];
        float e = ebuf[i];
        ebuf[i] = 0.f;
        if (m < 0) break;
        if (m != pm) {
          if (pm >= 0) atomicAdd(&out[pm], acs);
          acs = 0.f;
          pm = m;
        }
        acs += e + o2b0;
      }
      if (pm >= 0) atomicAdd(&out[pm], acs);
    }
  }
}

// ---- agg16[a] = (fp16) sum_{e: col=a} x16[row_e] * tabh[tq_e]
__global__ __launch_bounds__(256) void aggregate_k(
    const int* __restrict__ starts, const unsigned int* __restrict__ payload,
    const _Float16* __restrict__ x16, const _Float16* __restrict__ tabh,
    _Float16* __restrict__ agg16, int N) {
  int a = blockIdx.x * 4 + (threadIdx.x >> 6);
  if (a >= N) return;
  int lane = threadIdx.x & 63;
  int half = lane >> 5;
  int sl = lane & 31;
  int s = starts[a], e_end = starts[a + 1];
  float4 accf = make_float4(0.f, 0.f, 0.f, 0.f);
  const h4 z4 = {(_Float16)0.f, (_Float16)0.f, (_Float16)0.f, (_Float16)0.f};
  int i = s;
  for (; i + 16 <= e_end; i += 16) {
    unsigned int p[8];
#pragma unroll
    for (int u = 0; u < 8; u++) p[u] = payload[i + 2 * u + half];
    h4 tw[8], xr[8];
#pragma unroll
    for (int u = 0; u < 8; u++) {
      int tq = (int)(p[u] & 8191u);
      int r = (int)(p[u] >> 13);
      tw[u] = *(const h4*)&tabh[(size_t)tq * HID + sl * 4];
      xr[u] = *(const h4*)&x16[(size_t)r * HID + sl * 4];
    }
    h4 a0 = z4, a1 = z4, a2 = z4, a3 = z4;
    a0 += tw[0] * xr[0];
    a1 += tw[1] * xr[1];
    a2 += tw[2] * xr[2];
    a3 += tw[3] * xr[3];
    a0 += tw[4] * xr[4];
    a1 += tw[5] * xr[5];
    a2 += tw[6] * xr[6];
    a3 += tw[7] * xr[7];
    h4 b0 = a0 + a1, b1 = a2 + a3;
    accf.x += (float)b0.x + (float)b1.x;
    accf.y += (float)b0.y + (float)b1.y;
    accf.z += (float)b0.z + (float)b1.z;
    accf.w += (float)b0.w + (float)b1.w;
  }
  {
    h4 a0 = z4, a1 = z4;
    int k = 0;
    for (; i + 2 <= e_end; i += 2, k++) {
      unsigned int p = payload[i + half];
      int tq = (int)(p & 8191u);
      int r = (int)(p >> 13);
      h4 tw = *(const h4*)&tabh[(size_t)tq * HID + sl * 4];
      h4 xr = *(const h4*)&x16[(size_t)r * HID + sl * 4];
      if (k & 1) a1 += tw * xr; else a0 += tw * xr;
    }
    if (i < e_end && half == 0) {
      unsigned int p = payload[i];
      int tq = (int)(p & 8191u);
      int r = (int)(p >> 13);
      h4 tw = *(const h4*)&tabh[(size_t)tq * HID + sl * 4];
      h4 xr = *(const h4*)&x16[(size_t)r * HID + sl * 4];
      a0 += tw * xr;
    }
    h4 b0 = a0 + a1;
    accf.x += (float)b0.x;
    accf.y += (float)b0.y;
    accf.z += (float)b0.z;
    accf.w += (float)b0.w;
  }
  accf.x += __shfl_xor(accf.x, 32);
  accf.y += __shfl_xor(accf.y, 32);
  accf.z += __shfl_xor(accf.z, 32);
  accf.w += __shfl_xor(accf.w, 32);
  if (half == 0) {
    h4 o;
    o.x = (_Float16)accf.x; o.y = (_Float16)accf.y;
    o.z = (_Float16)accf.z; o.w = (_Float16)accf.w;
    *(h4*)&agg16[(size_t)a * HID + sl * 4] = o;
  }
}

extern "C" void kernel_launch(void* const* d_in, const int* in_sizes, int n_in,
                              void* d_out, int out_size, void* d_ws, size_t ws_size,
                              hipStream_t stream) {
  const int* z = (const int*)d_in[0];
  const float* pos = (const float*)d_in[1];
  const int* batch = (const int*)d_in[2];
  const int* eidx = (const int*)d_in[3];
  const float* emb = (const float*)d_in[4];
  const float* mlp1_w = (const float*)d_in[5];
  const float* mlp1_b = (const float*)d_in[6];
  const float* mlp2_w = (const float*)d_in[7];
  const float* mlp2_b = (const float*)d_in[8];
  const float* lin1_w = (const float*)d_in[9];
  const float* lin2_w = (const float*)d_in[10];
  const float* lin2_b = (const float*)d_in[11];
  const float* int_w = (const float*)d_in[12];
  const float* int_b = (const float*)d_in[13];
  const float* out1_w = (const float*)d_in[14];
  const float* out1_b = (const float*)d_in[15];
  const float* out2_w = (const float*)d_in[16];
  const float* out2_b = (const float*)d_in[17];
  float* out = (float*)d_out;

  const int N = in_sizes[0];
  const int E = in_sizes[3] / 2;
  const int* row = eidx;
  const int* col = eidx + E;
  const int nbuck = (N + 63) / 64;
  const int ntiles = (N + 31) / 32;

  char* ws = (char*)d_ws;
  size_t off = 0;
  auto alloc = [&](size_t bytes) -> void* {
    void* p = ws + off;
    off = (off + bytes + 255) & ~(size_t)255;
    return p;
  };
  _Float16* h16 = (_Float16*)alloc((size_t)N * HID * 2);
  _Float16* x16 = (_Float16*)alloc((size_t)N * HID * 2);   // doubles as y16
  size_t agg_bytes = (size_t)N * HID * 2;
  size_t tmp_bytes = (size_t)E * 8 + 16;
  void* agg_union = alloc(agg_bytes > tmp_bytes ? agg_bytes : tmp_bytes);
  _Float16* agg16 = (_Float16*)agg_union;
  unsigned long long* tmp = (unsigned long long*)agg_union;
  unsigned int* payload = (unsigned int*)alloc((size_t)E * 4 + 16);
  int* starts = (int*)alloc((size_t)(N + 1) * 4);
  int* bcount = (int*)alloc((size_t)nbuck * 4);
  int* bstart = (int*)alloc((size_t)(nbuck + 1) * 4);
  int* bcur = (int*)alloc((size_t)nbuck * 4);
  float* tab = (float*)alloc((size_t)3 * TBL * HID * 4);
  _Float16* tabh = (_Float16*)alloc((size_t)3 * TBL2 * HID * 2);
  _Float16* Wsw = (_Float16*)alloc((size_t)10 * 16384 * 2);
  (void)ws_size;

  hipMemsetAsync(bcount, 0, (size_t)nbuck * 4, stream);
  hipMemsetAsync(out, 0, (size_t)out_size * 4, stream);

  build_table_k<<<3 * TBL, 128, 0, stream>>>(mlp1_w, mlp1_b, mlp2_w, mlp2_b, tab);
  upsample_k<<<(3 * TBL2 * HID + 255) / 256, 256, 0, stream>>>(tab, tabh);
  wswz10_k<<<10, 256, 0, stream>>>(lin1_w, lin2_w, int_w, out1_w, Wsw);
  bcount_k<<<(E + 2047) / 2048, 256, 0, stream>>>(col, bcount, E, nbuck);
  bucket_scan_k<<<1, 256, 0, stream>>>(bcount, bstart, bcur, nbuck, starts, N);
  scatterA_k<<<(E + 2047) / 2048, 256, 0, stream>>>(row, col, pos, bcur, tmp, E, nbuck);
  scatterB_k<<<nbuck, 256, 0, stream>>>(tmp, bstart, starts, payload, N);

  // persistent grid: exactly 2 tiles per block, all co-resident (4 blocks/CU cap)
  int pg = (ntiles + 1) / 2;
  if (pg > 1024) pg = 1024;
  for (int l = 0; l < 3; l++) {
    if (l == 0)
      lin_emb_p_k<<<pg, 256, 0, stream>>>(z, emb, Wsw, h16, x16, N, ntiles);
    else
      lin_p_k<<<pg, 256, 0, stream>>>(h16, Wsw + (size_t)l * 16384, x16, N, ntiles);
    aggregate_k<<<(N + 3) / 4, 256, 0, stream>>>(starts, payload, x16,
                                                 tabh + (size_t)l * TBL2 * HID, agg16, N);
    ssp_p_k<<<pg, 256, 0, stream>>>(agg16, Wsw + (size_t)(3 + l) * 16384,
                                    lin2_b + (size_t)l * HID, x16, N, ntiles);
    res_p_k<<<pg, 256, 0, stream>>>(x16, Wsw + (size_t)(6 + l) * 16384,
                                    int_b + (size_t)l * HID, h16, N, ntiles);
  }
  energy_p_k<<<pg, 256, 0, stream>>>(h16, Wsw + (size_t)9 * 16384, out1_b, out2_w,
                                     out2_b, batch, out, N, ntiles);
}

// Round 16
// 549.969 us; speedup vs baseline: 1.0375x; 1.0227x over previous
//
#include <hip/hip_runtime.h>
#include <math.h>

#define HID 128
#define NGAUSS 50
#define TBL 2048
#define TBL2 4096   // 1 MB/layer fp16 table: frees L2 for the x16 gather stream
#define DMAX 8.6605f
#define LDX 136
#define PGRID 768

typedef _Float16 h4 __attribute__((ext_vector_type(4)));
typedef _Float16 f16x8 __attribute__((ext_vector_type(8)));
typedef float f32x4 __attribute__((ext_vector_type(4)));

__device__ __forceinline__ float sspf(float x) {
  float ax = fabsf(x);
  return fmaxf(x, 0.0f) + log1pf(expf(-ax)) - 0.69314718055994530942f;
}

// ---- Build W(d) lookup table (fp32, coarse): tab[l][ti][j]
__global__ __launch_bounds__(128) void build_table_k(
    const float* __restrict__ w1, const float* __restrict__ b1,
    const float* __restrict__ w2, const float* __restrict__ b2,
    float* __restrict__ tab) {
  int l = blockIdx.x >> 11;
  int ti = blockIdx.x & (TBL - 1);
  int j = threadIdx.x;
  __shared__ float rbf[NGAUSS];
  __shared__ float v1[HID];
  const float step = DMAX / (float)(TBL - 1);
  float d = ti * step;
  if (j < NGAUSS) {
    const float gstep = 10.0f / 49.0f;
    const float gcoeff = -12.005f;
    float diff = d - j * gstep;
    rbf[j] = expf(gcoeff * diff * diff);
  }
  __syncthreads();
  float s = b1[l * HID + j];
  const float* w1p = w1 + l * NGAUSS * HID + j;
  for (int g = 0; g < NGAUSS; g++) s = fmaf(rbf[g], w1p[g * HID], s);
  v1[j] = sspf(s);
  __syncthreads();
  float s2 = b2[l * HID + j];
  const float* w2p = w2 + l * HID * HID + j;
  for (int k = 0; k < HID; k++) s2 = fmaf(v1[k], w2p[k * HID], s2);
  float C = 0.5f * (cosf(d * 0.3141592653589793f) + 1.0f);
  tab[((size_t)l * TBL + ti) * HID + j] = s2 * C;
}

// ---- upsample coarse fp32 lerp table -> fine fp16 nearest table [l][TBL2][HID]
__global__ __launch_bounds__(256) void upsample_k(
    const float* __restrict__ tab, _Float16* __restrict__ tabh) {
  int idx = blockIdx.x * 256 + threadIdx.x;
  if (idx >= 3 * TBL2 * HID) return;
  int ch = idx & 127;
  int i = (idx >> 7) & (TBL2 - 1);
  int l = idx / (TBL2 * HID);
  float t = (float)i * ((float)(TBL - 1) / (float)(TBL2 - 1));
  int i0 = min((int)t, TBL - 2);
  float f = t - (float)i0;
  const float* base = tab + ((size_t)l * TBL + i0) * HID + ch;
  tabh[idx] = (_Float16)fmaf(f, base[HID] - base[0], base[0]);
}

// ---- swizzle 9 128x128 weights + out1_w (128x64) into B-fragment order
__global__ __launch_bounds__(256) void wswz10_k(
    const float* __restrict__ lin1, const float* __restrict__ lin2,
    const float* __restrict__ intw, const float* __restrict__ out1w,
    _Float16* __restrict__ out) {
  int b = blockIdx.x;
  int t = threadIdx.x;
  if (b < 9) {
    const float* src = (b < 3 ? lin1 : (b < 6 ? lin2 : intw)) + (size_t)(b % 3) * HID * HID;
    _Float16* dst = out + (size_t)b * 16384;
    for (int i = t; i < 16384; i += 256) {
      int j = i & 7;
      int lane = (i >> 3) & 63;
      int kk = (i >> 9) & 3;
      int ntc = i >> 11;
      int n = ntc * 16 + (lane & 15);
      int k = kk * 32 + (lane >> 4) * 8 + j;
      dst[i] = (_Float16)src[k * HID + n];
    }
  } else {
    _Float16* dst = out + (size_t)9 * 16384;
    for (int i = t; i < 8192; i += 256) {
      int j = i & 7;
      int lane = (i >> 3) & 63;
      int kk = (i >> 9) & 3;
      int ntc = i >> 11;
      int n = ntc * 16 + (lane & 15);
      int k = kk * 32 + (lane >> 4) * 8 + j;
      dst[i] = (_Float16)out1w[k * 64 + n];
    }
  }
}

// ---- h16 = (fp16) emb[z]
__global__ __launch_bounds__(256) void emb_gather_k(
    const int* __restrict__ z, const float* __restrict__ emb,
    _Float16* __restrict__ h16, int N) {
  int i4 = blockIdx.x * 256 + threadIdx.x;
  if (i4 >= N * 32) return;
  int a = i4 >> 5;
  float4 v = ((const float4*)emb)[z[a] * 32 + (i4 & 31)];
  h4 o;
  o.x = (_Float16)v.x; o.y = (_Float16)v.y;
  o.z = (_Float16)v.z; o.w = (_Float16)v.w;
  ((h4*)h16)[i4] = o;
}

// ---- bucket (col>>6) histogram, LDS-aggregated
__global__ __launch_bounds__(256) void bcount_k(
    const int* __restrict__ col, int* __restrict__ bcount, int E, int nbuck) {
  __shared__ int hist[1024];
  int t = threadIdx.x;
  int e0 = blockIdx.x * 2048;
  for (int j = t; j < nbuck; j += 256) hist[j] = 0;
  __syncthreads();
#pragma unroll
  for (int u = 0; u < 8; u++) {
    int e = e0 + u * 256 + t;
    if (e < E) atomicAdd(&hist[col[e] >> 6], 1);
  }
  __syncthreads();
  for (int j = t; j < nbuck; j += 256)
    if (hist[j]) atomicAdd(&bcount[j], hist[j]);
}

// ---- exclusive scan of bucket counts (single block)
__global__ __launch_bounds__(256) void bucket_scan_k(
    const int* __restrict__ bcount, int* __restrict__ bstart,
    int* __restrict__ bcur, int nbuck, int* __restrict__ starts, int N) {
  __shared__ int sh[256];
  int t = threadIdx.x;
  int chunk = (nbuck + 255) / 256;
  int b0 = t * chunk;
  int c[8];
  int s = 0;
  for (int j = 0; j < chunk; j++) {
    int idx = b0 + j;
    int v = (idx < nbuck) ? bcount[idx] : 0;
    c[j] = v;
    s += v;
  }
  sh[t] = s;
  __syncthreads();
  for (int o = 1; o < 256; o <<= 1) {
    int v = (t >= o) ? sh[t - o] : 0;
    __syncthreads();
    sh[t] += v;
    __syncthreads();
  }
  int p = (t == 0) ? 0 : sh[t - 1];
  for (int j = 0; j < chunk; j++) {
    int idx = b0 + j;
    if (idx < nbuck) {
      bstart[idx] = p;
      bcur[idx] = p;
      p += c[j];
    }
  }
  if (t == 255) {
    bstart[nbuck] = p;
    starts[N] = p;
  }
}

// ---- level-1 scatter: distance inline, key64 into 64-atom bucket chunks
__global__ __launch_bounds__(256) void scatterA_k(
    const int* __restrict__ row, const int* __restrict__ col,
    const float* __restrict__ pos, int* __restrict__ bcur,
    unsigned long long* __restrict__ tmp, int E, int nbuck) {
  __shared__ int hist[1024];
  __shared__ int base[1024];
  int t = threadIdx.x;
  int e0 = blockIdx.x * 2048;
  for (int j = t; j < nbuck; j += 256) hist[j] = 0;
  __syncthreads();
  int bkt[8];
  int rnk[8];
  unsigned long long key[8];
#pragma unroll
  for (int u = 0; u < 8; u++) {
    int e = e0 + u * 256 + t;
    bkt[u] = -1;
    if (e < E) {
      int r = row[e], c = col[e];
      float dx = pos[r * 3 + 0] - pos[c * 3 + 0];
      float dy = pos[r * 3 + 1] - pos[c * 3 + 1];
      float dz = pos[r * 3 + 2] - pos[c * 3 + 2];
      float d = sqrtf(dx * dx + dy * dy + dz * dz);
      const float inv2 = (float)(TBL2 - 1) / DMAX;
      int q = min((int)(d * inv2 + 0.5f), TBL2 - 1);
      unsigned int pay = ((unsigned int)r << 13) | (unsigned int)q;
      key[u] = ((unsigned long long)pay << 6) | (unsigned long long)(c & 63);
      bkt[u] = c >> 6;
      rnk[u] = atomicAdd(&hist[bkt[u]], 1);
    }
  }
  __syncthreads();
  for (int j = t; j < nbuck; j += 256)
    base[j] = hist[j] ? atomicAdd(&bcur[j], hist[j]) : 0;
  __syncthreads();
#pragma unroll
  for (int u = 0; u < 8; u++)
    if (bkt[u] >= 0) tmp[(size_t)base[bkt[u]] + rnk[u]] = key[u];
}

// ---- level-2: per-bucket per-atom counts -> starts, then local scatter
__global__ __launch_bounds__(256) void scatterB_k(
    const unsigned long long* __restrict__ tmp, const int* __restrict__ bstart,
    int* __restrict__ starts, unsigned int* __restrict__ payload, int N) {
  int j = blockIdx.x;
  int t = threadIdx.x;
  __shared__ int cnt[64];
  __shared__ int cur[64];
  int rs = bstart[j], re = bstart[j + 1];
  if (t < 64) cnt[t] = 0;
  __syncthreads();
  for (int e = rs + t; e < re; e += 256)
    atomicAdd(&cnt[(int)(tmp[e] & 63)], 1);
  __syncthreads();
  if (t < 64) {
    int mine = cnt[t];
    int v = mine;
    for (int o = 1; o < 64; o <<= 1) {
      int u = __shfl_up(v, o, 64);
      if (t >= o) v += u;
    }
    int excl = v - mine;
    int c = j * 64 + t;
    if (c < N) starts[c] = rs + excl;
    cur[t] = rs + excl;
  }
  __syncthreads();
  for (int e = rs + t; e < re; e += 256) {
    unsigned long long k = tmp[e];
    int p = atomicAdd(&cur[(int)(k & 63)], 1);
    payload[p] = (unsigned int)(k >> 6);
  }
}

// ======== persistent GEMM kernels: 32-atom tiles, weights streamed from L2 =====
// 4 waves: g=w&1 (atom group of 16), c=w>>1 (col half of 64)

// ---- x16 = in16 @ W   (fp16 in, fp16 out; no bias/act)
__global__ __launch_bounds__(256, 4) void lin_p_k(
    const _Float16* __restrict__ in16, const _Float16* __restrict__ Wg,
    _Float16* __restrict__ out16, int N, int ntiles) {
  __shared__ __align__(16) _Float16 Xs[32 * LDX];
  __shared__ __align__(16) _Float16 Ys[32 * LDX];
  int t = threadIdx.x;
  int lane = t & 63, w = t >> 6;
  int g = w & 1, c = w >> 1;
  int mrow = lane & 15, quad = lane >> 4;
  f32x4 zero = {0.f, 0.f, 0.f, 0.f};
  for (int tile = blockIdx.x; tile < ntiles; tile += gridDim.x) {
    int a0 = tile * 32;
#pragma unroll
    for (int p = 0; p < 2; p++) {
      int id = t + p * 256;
      int a = id >> 4, kg = id & 15;
      uint4 v = make_uint4(0, 0, 0, 0);
      if (a0 + a < N) v = ((const uint4*)in16)[(size_t)(a0 + a) * 16 + kg];
      *(uint4*)&Xs[a * LDX + kg * 8] = v;
    }
    __syncthreads();
    f16x8 af[4];
#pragma unroll
    for (int kk = 0; kk < 4; kk++)
      af[kk] = *(const f16x8*)&Xs[(g * 16 + mrow) * LDX + kk * 32 + quad * 8];
    f32x4 acc[4];
#pragma unroll
    for (int i = 0; i < 4; i++) acc[i] = zero;
#pragma unroll
    for (int kk = 0; kk < 4; kk++) {
#pragma unroll
      for (int nt = 0; nt < 4; nt++) {
        f16x8 bf = *(const f16x8*)(Wg + ((((c * 4 + nt) * 4 + kk) << 9) + lane * 8));
        acc[nt] = __builtin_amdgcn_mfma_f32_16x16x32_f16(af[kk], bf, acc[nt], 0, 0, 0);
      }
    }
#pragma unroll
    for (int nt = 0; nt < 4; nt++) {
      int colv = c * 64 + nt * 16 + mrow;
#pragma unroll
      for (int r = 0; r < 4; r++)
        Ys[(g * 16 + quad * 4 + r) * LDX + colv] = (_Float16)acc[nt][r];
    }
    __syncthreads();
#pragma unroll
    for (int p = 0; p < 2; p++) {
      int id = t + p * 256;
      int a = id >> 4, kg = id & 15;
      if (a0 + a < N)
        ((uint4*)out16)[(size_t)(a0 + a) * 16 + kg] = *(uint4*)&Ys[a * LDX + kg * 8];
    }
  }
}

// ---- y16 = (fp16) ssp(agg16 @ W + b)
__global__ __launch_bounds__(256, 4) void ssp_p_k(
    const _Float16* __restrict__ agg16, const _Float16* __restrict__ Wg,
    const float* __restrict__ bias, _Float16* __restrict__ y16, int N, int ntiles) {
  __shared__ __align__(16) _Float16 Xs[32 * LDX];
  __shared__ __align__(16) _Float16 Ys[32 * LDX];
  int t = threadIdx.x;
  int lane = t & 63, w = t >> 6;
  int g = w & 1, c = w >> 1;
  int mrow = lane & 15, quad = lane >> 4;
  float br[4];
#pragma unroll
  for (int nt = 0; nt < 4; nt++) br[nt] = bias[c * 64 + nt * 16 + mrow];
  f32x4 zero = {0.f, 0.f, 0.f, 0.f};
  for (int tile = blockIdx.x; tile < ntiles; tile += gridDim.x) {
    int a0 = tile * 32;
#pragma unroll
    for (int p = 0; p < 2; p++) {
      int id = t + p * 256;
      int a = id >> 4, kg = id & 15;
      uint4 v = make_uint4(0, 0, 0, 0);
      if (a0 + a < N) v = ((const uint4*)agg16)[(size_t)(a0 + a) * 16 + kg];
      *(uint4*)&Xs[a * LDX + kg * 8] = v;
    }
    __syncthreads();
    f16x8 af[4];
#pragma unroll
    for (int kk = 0; kk < 4; kk++)
      af[kk] = *(const f16x8*)&Xs[(g * 16 + mrow) * LDX + kk * 32 + quad * 8];
    f32x4 acc[4];
#pragma unroll
    for (int i = 0; i < 4; i++) acc[i] = zero;
#pragma unroll
    for (int kk = 0; kk < 4; kk++) {
#pragma unroll
      for (int nt = 0; nt < 4; nt++) {
        f16x8 bf = *(const f16x8*)(Wg + ((((c * 4 + nt) * 4 + kk) << 9) + lane * 8));
        acc[nt] = __builtin_amdgcn_mfma_f32_16x16x32_f16(af[kk], bf, acc[nt], 0, 0, 0);
      }
    }
#pragma unroll
    for (int nt = 0; nt < 4; nt++) {
      int colv = c * 64 + nt * 16 + mrow;
#pragma unroll
      for (int r = 0; r < 4; r++)
        Ys[(g * 16 + quad * 4 + r) * LDX + colv] = (_Float16)sspf(acc[nt][r] + br[nt]);
    }
    __syncthreads();
#pragma unroll
    for (int p = 0; p < 2; p++) {
      int id = t + p * 256;
      int a = id >> 4, kg = id & 15;
      if (a0 + a < N)
        ((uint4*)y16)[(size_t)(a0 + a) * 16 + kg] = *(uint4*)&Ys[a * LDX + kg * 8];
    }
  }
}

// ---- h16 += y16 @ W + b   (fp16 RMW on h)
__global__ __launch_bounds__(256, 4) void res_p_k(
    const _Float16* __restrict__ y16, const _Float16* __restrict__ Wg,
    const float* __restrict__ bias, _Float16* __restrict__ h16, int N, int ntiles) {
  __shared__ __align__(16) _Float16 Xs[32 * LDX];
  __shared__ __align__(16) _Float16 Ys[32 * LDX];
  int t = threadIdx.x;
  int lane = t & 63, w = t >> 6;
  int g = w & 1, c = w >> 1;
  int mrow = lane & 15, quad = lane >> 4;
  float br[4];
#pragma unroll
  for (int nt = 0; nt < 4; nt++) br[nt] = bias[c * 64 + nt * 16 + mrow];
  f32x4 zero = {0.f, 0.f, 0.f, 0.f};
  for (int tile = blockIdx.x; tile < ntiles; tile += gridDim.x) {
    int a0 = tile * 32;
#pragma unroll
    for (int p = 0; p < 2; p++) {
      int id = t + p * 256;
      int a = id >> 4, kg = id & 15;
      uint4 v = make_uint4(0, 0, 0, 0);
      if (a0 + a < N) v = ((const uint4*)y16)[(size_t)(a0 + a) * 16 + kg];
      *(uint4*)&Xs[a * LDX + kg * 8] = v;
    }
    __syncthreads();
    f16x8 af[4];
#pragma unroll
    for (int kk = 0; kk < 4; kk++)
      af[kk] = *(const f16x8*)&Xs[(g * 16 + mrow) * LDX + kk * 32 + quad * 8];
    f32x4 acc[4];
#pragma unroll
    for (int i = 0; i < 4; i++) acc[i] = zero;
#pragma unroll
    for (int kk = 0; kk < 4; kk++) {
#pragma unroll
      for (int nt = 0; nt < 4; nt++) {
        f16x8 bf = *(const f16x8*)(Wg + ((((c * 4 + nt) * 4 + kk) << 9) + lane * 8));
        acc[nt] = __builtin_amdgcn_mfma_f32_16x16x32_f16(af[kk], bf, acc[nt], 0, 0, 0);
      }
    }
#pragma unroll
    for (int nt = 0; nt < 4; nt++) {
      int colv = c * 64 + nt * 16 + mrow;
#pragma unroll
      for (int r = 0; r < 4; r++)
        Ys[(g * 16 + quad * 4 + r) * LDX + colv] = (_Float16)(acc[nt][r] + br[nt]);
    }
    __syncthreads();
#pragma unroll
    for (int p = 0; p < 2; p++) {
      int id = t + p * 256;
      int a = id >> 4, kg = id & 15;
      if (a0 + a < N) {
        f16x8 hv = *(const f16x8*)&((const uint4*)h16)[(size_t)(a0 + a) * 16 + kg];
        f16x8 yv = *(f16x8*)&Ys[a * LDX + kg * 8];
        f16x8 o;
#pragma unroll
        for (int j = 0; j < 8; j++) o[j] = (_Float16)((float)hv[j] + (float)yv[j]);
        ((uint4*)h16)[(size_t)(a0 + a) * 16 + kg] = *(uint4*)&o;
      }
    }
  }
}

// ---- energy + segmented molecule flush (batch sorted: <=3 atomics per tile)
__global__ __launch_bounds__(256, 4) void energy_p_k(
    const _Float16* __restrict__ h16, const _Float16* __restrict__ Wg,
    const float* __restrict__ o1b, const float* __restrict__ o2w,
    const float* __restrict__ o2b, const int* __restrict__ batch,
    float* __restrict__ out, int N, int ntiles) {
  __shared__ __align__(16) _Float16 Xs[32 * LDX];
  __shared__ float ebuf[32];
  __shared__ int bat[32];
  int t = threadIdx.x;
  int lane = t & 63, w = t >> 6;
  int g = w & 1, c = w >> 1;
  int mrow = lane & 15, quad = lane >> 4;
  float br[2], wr[2];
#pragma unroll
  for (int nt = 0; nt < 2; nt++) {
    int colv = c * 32 + nt * 16 + mrow;
    br[nt] = o1b[colv];
    wr[nt] = o2w[colv];
  }
  float o2b0 = o2b[0];
  if (t < 32) ebuf[t] = 0.f;
  __syncthreads();
  f32x4 zero = {0.f, 0.f, 0.f, 0.f};
  for (int tile = blockIdx.x; tile < ntiles; tile += gridDim.x) {
    int a0 = tile * 32;
#pragma unroll
    for (int p = 0; p < 2; p++) {
      int id = t + p * 256;
      int a = id >> 4, kg = id & 15;
      uint4 v = make_uint4(0, 0, 0, 0);
      if (a0 + a < N) v = ((const uint4*)h16)[(size_t)(a0 + a) * 16 + kg];
      *(uint4*)&Xs[a * LDX + kg * 8] = v;
    }
    if (t < 32) bat[t] = (a0 + t < N) ? batch[a0 + t] : -1;
    __syncthreads();
    f16x8 af[4];
#pragma unroll
    for (int kk = 0; kk < 4; kk++)
      af[kk] = *(const f16x8*)&Xs[(g * 16 + mrow) * LDX + kk * 32 + quad * 8];
    f32x4 acc[2];
    acc[0] = zero; acc[1] = zero;
#pragma unroll
    for (int kk = 0; kk < 4; kk++) {
#pragma unroll
      for (int nt = 0; nt < 2; nt++) {
        f16x8 bf = *(const f16x8*)(Wg + ((((c * 2 + nt) * 4 + kk) << 9) + lane * 8));
        acc[nt] = __builtin_amdgcn_mfma_f32_16x16x32_f16(af[kk], bf, acc[nt], 0, 0, 0);
      }
    }
    float ss[4] = {0.f, 0.f, 0.f, 0.f};
#pragma unroll
    for (int nt = 0; nt < 2; nt++)
#pragma unroll
      for (int r = 0; r < 4; r++) ss[r] += sspf(acc[nt][r] + br[nt]) * wr[nt];
#pragma unroll
    for (int r = 0; r < 4; r++) {
      ss[r] += __shfl_xor(ss[r], 1);
      ss[r] += __shfl_xor(ss[r], 2);
      ss[r] += __shfl_xor(ss[r], 4);
      ss[r] += __shfl_xor(ss[r], 8);
      if (mrow == 0) atomicAdd(&ebuf[g * 16 + quad * 4 + r], ss[r]);
    }
    __syncthreads();
    if (t == 0) {
      float acs = 0.f;
      int pm = -1;
      for (int i = 0; i < 32; i++) {
        int m = bat[i];
        float e = ebuf[i];
        ebuf[i] = 0.f;
        if (m < 0) break;
        if (m != pm) {
          if (pm >= 0) atomicAdd(&out[pm], acs);
          acs = 0.f;
          pm = m;
        }
        acs += e + o2b0;
      }
      if (pm >= 0) atomicAdd(&out[pm], acs);
    }
  }
}

// ---- agg16[a] = (fp16) sum_{e: col=a} x16[row_e] * tabh[tq_e]
__global__ __launch_bounds__(256) void aggregate_k(
    const int* __restrict__ starts, const unsigned int* __restrict__ payload,
    const _Float16* __restrict__ x16, const _Float16* __restrict__ tabh,
    _Float16* __restrict__ agg16, int N) {
  int a = blockIdx.x * 4 + (threadIdx.x >> 6);
  if (a >= N) return;
  int lane = threadIdx.x & 63;
  int half = lane >> 5;
  int sl = lane & 31;
  int s = starts[a], e_end = starts[a + 1];
  float4 accf = make_float4(0.f, 0.f, 0.f, 0.f);
  const h4 z4 = {(_Float16)0.f, (_Float16)0.f, (_Float16)0.f, (_Float16)0.f};
  int i = s;
  for (; i + 16 <= e_end; i += 16) {
    unsigned int p[8];
#pragma unroll
    for (int u = 0; u < 8; u++) p[u] = payload[i + 2 * u + half];
    h4 tw[8], xr[8];
#pragma unroll
    for (int u = 0; u < 8; u++) {
      int tq = (int)(p[u] & 8191u);
      int r = (int)(p[u] >> 13);
      tw[u] = *(const h4*)&tabh[(size_t)tq * HID + sl * 4];
      xr[u] = *(const h4*)&x16[(size_t)r * HID + sl * 4];
    }
    h4 a0 = z4, a1 = z4, a2 = z4, a3 = z4;
    a0 += tw[0] * xr[0];
    a1 += tw[1] * xr[1];
    a2 += tw[2] * xr[2];
    a3 += tw[3] * xr[3];
    a0 += tw[4] * xr[4];
    a1 += tw[5] * xr[5];
    a2 += tw[6] * xr[6];
    a3 += tw[7] * xr[7];
    h4 b0 = a0 + a1, b1 = a2 + a3;
    accf.x += (float)b0.x + (float)b1.x;
    accf.y += (float)b0.y + (float)b1.y;
    accf.z += (float)b0.z + (float)b1.z;
    accf.w += (float)b0.w + (float)b1.w;
  }
  {
    h4 a0 = z4, a1 = z4;
    int k = 0;
    for (; i + 2 <= e_end; i += 2, k++) {
      unsigned int p = payload[i + half];
      int tq = (int)(p & 8191u);
      int r = (int)(p >> 13);
      h4 tw = *(const h4*)&tabh[(size_t)tq * HID + sl * 4];
      h4 xr = *(const h4*)&x16[(size_t)r * HID + sl * 4];
      if (k & 1) a1 += tw * xr; else a0 += tw * xr;
    }
    if (i < e_end && half == 0) {
      unsigned int p = payload[i];
      int tq = (int)(p & 8191u);
      int r = (int)(p >> 13);
      h4 tw = *(const h4*)&tabh[(size_t)tq * HID + sl * 4];
      h4 xr = *(const h4*)&x16[(size_t)r * HID + sl * 4];
      a0 += tw * xr;
    }
    h4 b0 = a0 + a1;
    accf.x += (float)b0.x;
    accf.y += (float)b0.y;
    accf.z += (float)b0.z;
    accf.w += (float)b0.w;
  }
  accf.x += __shfl_xor(accf.x, 32);
  accf.y += __shfl_xor(accf.y, 32);
  accf.z += __shfl_xor(accf.z, 32);
  accf.w += __shfl_xor(accf.w, 32);
  if (half == 0) {
    h4 o;
    o.x = (_Float16)accf.x; o.y = (_Float16)accf.y;
    o.z = (_Float16)accf.z; o.w = (_Float16)accf.w;
    *(h4*)&agg16[(size_t)a * HID + sl * 4] = o;
  }
}

extern "C" void kernel_launch(void* const* d_in, const int* in_sizes, int n_in,
                              void* d_out, int out_size, void* d_ws, size_t ws_size,
                              hipStream_t stream) {
  const int* z = (const int*)d_in[0];
  const float* pos = (const float*)d_in[1];
  const int* batch = (const int*)d_in[2];
  const int* eidx = (const int*)d_in[3];
  const float* emb = (const float*)d_in[4];
  const float* mlp1_w = (const float*)d_in[5];
  const float* mlp1_b = (const float*)d_in[6];
  const float* mlp2_w = (const float*)d_in[7];
  const float* mlp2_b = (const float*)d_in[8];
  const float* lin1_w = (const float*)d_in[9];
  const float* lin2_w = (const float*)d_in[10];
  const float* lin2_b = (const float*)d_in[11];
  const float* int_w = (const float*)d_in[12];
  const float* int_b = (const float*)d_in[13];
  const float* out1_w = (const float*)d_in[14];
  const float* out1_b = (const float*)d_in[15];
  const float* out2_w = (const float*)d_in[16];
  const float* out2_b = (const float*)d_in[17];
  float* out = (float*)d_out;

  const int N = in_sizes[0];
  const int E = in_sizes[3] / 2;
  const int* row = eidx;
  const int* col = eidx + E;
  const int nbuck = (N + 63) / 64;
  const int ntiles = (N + 31) / 32;

  char* ws = (char*)d_ws;
  size_t off = 0;
  auto alloc = [&](size_t bytes) -> void* {
    void* p = ws + off;
    off = (off + bytes + 255) & ~(size_t)255;
    return p;
  };
  _Float16* h16 = (_Float16*)alloc((size_t)N * HID * 2);
  _Float16* x16 = (_Float16*)alloc((size_t)N * HID * 2);   // doubles as y16
  size_t agg_bytes = (size_t)N * HID * 2;
  size_t tmp_bytes = (size_t)E * 8 + 16;
  void* agg_union = alloc(agg_bytes > tmp_bytes ? agg_bytes : tmp_bytes);
  _Float16* agg16 = (_Float16*)agg_union;
  unsigned long long* tmp = (unsigned long long*)agg_union;
  unsigned int* payload = (unsigned int*)alloc((size_t)E * 4 + 16);
  int* starts = (int*)alloc((size_t)(N + 1) * 4);
  int* bcount = (int*)alloc((size_t)nbuck * 4);
  int* bstart = (int*)alloc((size_t)(nbuck + 1) * 4);
  int* bcur = (int*)alloc((size_t)nbuck * 4);
  float* tab = (float*)alloc((size_t)3 * TBL * HID * 4);
  _Float16* tabh = (_Float16*)alloc((size_t)3 * TBL2 * HID * 2);
  _Float16* Wsw = (_Float16*)alloc((size_t)10 * 16384 * 2);
  (void)ws_size;

  hipMemsetAsync(bcount, 0, (size_t)nbuck * 4, stream);
  hipMemsetAsync(out, 0, (size_t)out_size * 4, stream);

  build_table_k<<<3 * TBL, 128, 0, stream>>>(mlp1_w, mlp1_b, mlp2_w, mlp2_b, tab);
  upsample_k<<<(3 * TBL2 * HID + 255) / 256, 256, 0, stream>>>(tab, tabh);
  wswz10_k<<<10, 256, 0, stream>>>(lin1_w, lin2_w, int_w, out1_w, Wsw);
  emb_gather_k<<<(N * 32 + 255) / 256, 256, 0, stream>>>(z, emb, h16, N);
  bcount_k<<<(E + 2047) / 2048, 256, 0, stream>>>(col, bcount, E, nbuck);
  bucket_scan_k<<<1, 256, 0, stream>>>(bcount, bstart, bcur, nbuck, starts, N);
  scatterA_k<<<(E + 2047) / 2048, 256, 0, stream>>>(row, col, pos, bcur, tmp, E, nbuck);
  scatterB_k<<<nbuck, 256, 0, stream>>>(tmp, bstart, starts, payload, N);

  int pg = PGRID < ntiles ? PGRID : ntiles;
  for (int l = 0; l < 3; l++) {
    lin_p_k<<<pg, 256, 0, stream>>>(h16, Wsw + (size_t)l * 16384, x16, N, ntiles);
    aggregate_k<<<(N + 3) / 4, 256, 0, stream>>>(starts, payload, x16,
                                                 tabh + (size_t)l * TBL2 * HID, agg16, N);
    ssp_p_k<<<pg, 256, 0, stream>>>(agg16, Wsw + (size_t)(3 + l) * 16384,
                                    lin2_b + (size_t)l * HID, x16, N, ntiles);
    res_p_k<<<pg, 256, 0, stream>>>(x16, Wsw + (size_t)(6 + l) * 16384,
                                    int_b + (size_t)l * HID, h16, N, ntiles);
  }
  energy_p_k<<<pg, 256, 0, stream>>>(h16, Wsw + (size_t)9 * 16384, out1_b, out2_w,
                                     out2_b, batch, out, N, ntiles);
}